// Round 6
// baseline (188.355 us; speedup 1.0000x reference)
//
#include <hip/hip_runtime.h>
#include <hip/hip_bf16.h>
#include <hip/hip_fp16.h>

// B=2, S=2048, DIM=1024, H=16, DH=64. Output f32; inputs runtime-detected
// (bf16/f32/f16) and canonicalized to bf16 in ws.
//
// ws layout (bf16 elems):
//  Xc @ 0 | Wq @ 4194304 | Wk @ 5242880 | Wv @ 6291456
//  bq @ 7340032  bk @ 7341056  bv @ 7342080  ga @ 7343104  be @ 7344128
//  Qw @ 7345152 | Kw @ 11539456 | VTw @ 15733760 | Ow @ 19928064
//  flags (4 ints) @ byte 48244736

#define GL_LDS16(g, l) \
  __builtin_amdgcn_global_load_lds((const __attribute__((address_space(1))) void*)(g), \
                                   (__attribute__((address_space(3))) void*)(l), 16, 0, 0)

typedef float f32x4 __attribute__((ext_vector_type(4)));
typedef __bf16 bf16x8 __attribute__((ext_vector_type(8)));
typedef unsigned short u16;
typedef u16 u16x4 __attribute__((ext_vector_type(4)));
typedef u16 u16x8 __attribute__((ext_vector_type(8)));
typedef unsigned int u32;

static __device__ __forceinline__ float bf2f(u16 u) {
  u32 x = ((u32)u) << 16;
  return __builtin_bit_cast(float, x);
}
static __device__ __forceinline__ u16 f2bf(float f) {
  __hip_bfloat16 h = __float2bfloat16(f);
  return __builtin_bit_cast(u16, h);
}

// ---------------- signal (host-detected problems) ----------------
__global__ __launch_bounds__(256) void fill_signal(float* __restrict__ out, float v) {
  int i = blockIdx.x * 256 + threadIdx.x;
  if (i < 4194304) out[i] = v;
}

// ---------------- dtype detection (3-way) ----------------
__global__ __launch_bounds__(256) void detect_dtype(const u16* __restrict__ emb,
                                                    int* __restrict__ flags) {
  const int tid = threadIdx.x;
  u32 maxexp = 0;
  float sum = 0.f, sumsq = 0.f;
  for (int i = 0; i < 64; i++) {
    u16 u = emb[tid * 64 + i];
    u32 e = (u >> 7) & 0xFF;
    maxexp = maxexp > e ? maxexp : e;
    float ef = (float)e;
    sum += ef; sumsq += ef * ef;
  }
  for (int m = 1; m < 64; m <<= 1) {
    u32 o = (u32)__shfl_xor((int)maxexp, m);
    maxexp = maxexp > o ? maxexp : o;
    sum += __shfl_xor(sum, m);
    sumsq += __shfl_xor(sumsq, m);
  }
  __shared__ u32 rm[4];
  __shared__ float rs[4], rq[4];
  if ((tid & 63) == 0) { rm[tid >> 6] = maxexp; rs[tid >> 6] = sum; rq[tid >> 6] = sumsq; }
  __syncthreads();
  if (tid == 0) {
    u32 mx = rm[0]; float s = rs[0], q = rq[0];
    for (int i = 1; i < 4; i++) {
      mx = mx > rm[i] ? mx : rm[i];
      s += rs[i]; q += rq[i];
    }
    int fl;
    if (mx >= 160) fl = 1;                       // f32
    else {
      float mean = s * (1.0f / 16384.0f);
      float var = q * (1.0f / 16384.0f) - mean * mean;
      fl = (var > 60.0f) ? 2 : 0;                // f16 : bf16
    }
    flags[0] = fl;
  }
}

// ---------------- canonicalize inputs to bf16 ----------------
__global__ __launch_bounds__(256) void convert_inputs(
    const void* __restrict__ s0, const void* __restrict__ s1,
    const void* __restrict__ s2, const void* __restrict__ s3,
    const void* __restrict__ s4, const void* __restrict__ s5,
    const void* __restrict__ s6, const void* __restrict__ s7,
    const void* __restrict__ s8,
    u16* __restrict__ ws, const int* __restrict__ flags)
{
  const int t = blockIdx.x * 256 + threadIdx.x;  // unit = 8 elems
  if (t >= 918144) return;
  const void* src; size_t dstoff; int local;
  if      (t < 524288) { src = s0; dstoff = 0;       local = t; }
  else if (t < 655360) { src = s1; dstoff = 4194304; local = t - 524288; }
  else if (t < 786432) { src = s2; dstoff = 5242880; local = t - 655360; }
  else if (t < 917504) { src = s3; dstoff = 6291456; local = t - 786432; }
  else if (t < 917632) { src = s4; dstoff = 7340032; local = t - 917504; }
  else if (t < 917760) { src = s5; dstoff = 7341056; local = t - 917632; }
  else if (t < 917888) { src = s6; dstoff = 7342080; local = t - 917760; }
  else if (t < 918016) { src = s7; dstoff = 7343104; local = t - 917888; }
  else                 { src = s8; dstoff = 7344128; local = t - 918016; }
  const int fl = flags[0];
  u16x8 o;
  if (fl == 1) {
    const float* fp = (const float*)src + (size_t)local * 8;
#pragma unroll
    for (int i = 0; i < 8; i++) o[i] = f2bf(fp[i]);
  } else if (fl == 2) {
    u16x8 hv = *((const u16x8*)src + local);
#pragma unroll
    for (int i = 0; i < 8; i++) {
      u16 tmp = hv[i];
      float v = (float)__builtin_bit_cast(_Float16, tmp);
      o[i] = f2bf(v);
    }
  } else {
    o = *((const u16x8*)src + local);
  }
  *(u16x8*)&ws[dstoff + (size_t)local * 8] = o;
}

// ---------------- fused QKV projection ----------------
// 128x128 tile, BK=32, 4 waves 2x2. global_load_lds staging, double-buffered,
// chunk-XOR swizzle (linear LDS dest + swizzled source + swizzled read).
__global__ __launch_bounds__(256) void qkv_gemm(
    const u16* __restrict__ ws,
    u16* __restrict__ Qo, u16* __restrict__ Ko, u16* __restrict__ VTo)
{
  __shared__ __align__(16) u16 As[2][128 * 32];
  __shared__ __align__(16) u16 Bs[2][128 * 32];

  const int z = blockIdx.z;
  const u16* X    = ws;
  const u16* W    = ws + 4194304 + (size_t)z * 1048576;
  const u16* bias = ws + 7340032 + (size_t)z * 1024;

  const int tid = threadIdx.x;
  const int lane = tid & 63, wid = tid >> 6;
  const int wm = wid >> 1, wn = wid & 1;
  const int g = lane >> 4, cc = lane & 15;
  const int bm = blockIdx.x * 128, bn = blockIdx.y * 128;

  // staging: 512 16B chunks per tile, 2 per thread
  const int u0 = tid, u1 = tid + 256;
  const int ar0 = u0 >> 2, as0 = u0 & 3;
  const int ar1 = u1 >> 2, as1 = u1 & 3;
  const int ak0 = as0 ^ ((ar0 ^ (ar0 >> 2)) & 3);
  const int ak1 = as1 ^ ((ar1 ^ (ar1 >> 2)) & 3);

  f32x4 acc[4][4] = {};

#define G_STAGE(kt_, b_)                                                     \
  GL_LDS16(X + (size_t)(bm + ar0) * 1024 + (kt_) + ak0 * 8, &As[b_][u0 * 8]); \
  GL_LDS16(X + (size_t)(bm + ar1) * 1024 + (kt_) + ak1 * 8, &As[b_][u1 * 8]); \
  GL_LDS16(W + (size_t)(bn + ar0) * 1024 + (kt_) + ak0 * 8, &Bs[b_][u0 * 8]); \
  GL_LDS16(W + (size_t)(bn + ar1) * 1024 + (kt_) + ak1 * 8, &Bs[b_][u1 * 8]);

  G_STAGE(0, 0);
  int cur = 0;

  for (int kt = 0; kt < 1024; kt += 32) {
    __syncthreads();                 // drains vmcnt: buf[cur] staged
    if (kt + 32 < 1024) { G_STAGE(kt + 32, cur ^ 1); }

    bf16x8 a[4], b[4];
#pragma unroll
    for (int mf = 0; mf < 4; mf++) {
      int row = wm * 64 + mf * 16 + cc;
      int idx = row * 4 + (g ^ ((row ^ (row >> 2)) & 3));
      a[mf] = *(const bf16x8*)&As[cur][idx * 8];
    }
#pragma unroll
    for (int nf = 0; nf < 4; nf++) {
      int col = wn * 64 + nf * 16 + cc;
      int idx = col * 4 + (g ^ ((col ^ (col >> 2)) & 3));
      b[nf] = *(const bf16x8*)&Bs[cur][idx * 8];
    }
#pragma unroll
    for (int mf = 0; mf < 4; mf++)
#pragma unroll
      for (int nf = 0; nf < 4; nf++)
        acc[mf][nf] = __builtin_amdgcn_mfma_f32_16x16x32_bf16(a[mf], b[nf], acc[mf][nf], 0, 0, 0);
    cur ^= 1;
  }
#undef G_STAGE

  // C/D layout H1 (hardware-verified): col = lane&15, row = (lane>>4)*4 + reg
  float bb[4];
#pragma unroll
  for (int nf = 0; nf < 4; nf++) bb[nf] = bf2f(bias[bn + wn * 64 + nf * 16 + cc]);

#pragma unroll
  for (int mf = 0; mf < 4; mf++) {
#pragma unroll
    for (int nf = 0; nf < 4; nf++) {
      int i0 = bm + wm * 64 + mf * 16 + g * 4;    // rows i0..i0+3
      int j  = bn + wn * 64 + nf * 16 + cc;
      int h_ = j >> 6, d_ = j & 63;
      if (z == 2) {
        // V^T: 4 consecutive s per lane -> one 8B store
        int b_ = i0 >> 11, s_ = i0 & 2047;
        size_t hb = (size_t)(b_ * 16 + h_) * 131072;
        u16x4 pk;
#pragma unroll
        for (int r = 0; r < 4; r++) pk[r] = f2bf(acc[mf][nf][r] + bb[nf]);
        *(u16x4*)&VTo[hb + (size_t)d_ * 2048 + s_] = pk;
      } else {
        u16* dst = z ? Ko : Qo;
#pragma unroll
        for (int r = 0; r < 4; r++) {
          int i = i0 + r;
          int b_ = i >> 11, s_ = i & 2047;
          size_t hb = (size_t)(b_ * 16 + h_) * 131072;
          dst[hb + (size_t)s_ * 64 + d_] = f2bf(acc[mf][nf][r] + bb[nf]);
        }
      }
    }
  }
}

// ---------------- flash attention ----------------
// block = (64 q-rows, bh); 4 waves x 16 q-rows. global_load_lds K/V staging
// (dbuf, chunk-XOR swizzle), register online softmax, per-wave P bounce.
__global__ __launch_bounds__(256) void attn(
    const u16* __restrict__ Q, const u16* __restrict__ K,
    const u16* __restrict__ VT, u16* __restrict__ O)
{
  __shared__ __align__(16) u16 Ks[2][64 * 64];
  __shared__ __align__(16) u16 Vs[2][64 * 64];
  __shared__ __align__(16) u16 Pt[4][16 * 72];

  const int tid = threadIdx.x, lane = tid & 63, wid = tid >> 6;
  const int g = lane >> 4, cc = lane & 15;
  const int bh = blockIdx.y;
  const int q0 = blockIdx.x * 64 + wid * 16;
  const size_t base = (size_t)bh * 131072;

  bf16x8 qf[2];
#pragma unroll
  for (int kc = 0; kc < 2; kc++)
    qf[kc] = *(const bf16x8*)&Q[base + (size_t)(q0 + cc) * 64 + kc * 32 + g * 8];

  f32x4 o_acc[4] = {};
  float m_r[4], l_r[4];
#pragma unroll
  for (int r = 0; r < 4; r++) { m_r[r] = -1e30f; l_r[r] = 0.f; }

  // staging: 512 chunks per tile (64 rows x 8 chunks), 2 per thread
  const int u0 = tid, u1 = tid + 256;
  const int kr0 = u0 >> 3, ks0 = u0 & 7, kk0 = ks0 ^ (kr0 & 7);
  const int kr1 = u1 >> 3, ks1 = u1 & 7, kk1 = ks1 ^ (kr1 & 7);

#define A_STAGE(kv_, b_)                                                          \
  GL_LDS16(K  + base + (size_t)((kv_) + kr0) * 64 + kk0 * 8, &Ks[b_][u0 * 8]);    \
  GL_LDS16(K  + base + (size_t)((kv_) + kr1) * 64 + kk1 * 8, &Ks[b_][u1 * 8]);    \
  GL_LDS16(VT + base + (size_t)kr0 * 2048 + (kv_) + kk0 * 8, &Vs[b_][u0 * 8]);    \
  GL_LDS16(VT + base + (size_t)kr1 * 2048 + (kv_) + kk1 * 8, &Vs[b_][u1 * 8]);

  A_STAGE(0, 0);
  int cur = 0;

  for (int kv0 = 0; kv0 < 2048; kv0 += 64) {
    __syncthreads();                 // buf[cur] staged (vmcnt drained)
    if (kv0 + 64 < 2048) { A_STAGE(kv0 + 64, cur ^ 1); }

    // S = Q K^T : lane holds S[g*4+r][f*16+cc]
    f32x4 s_acc[4];
#pragma unroll
    for (int f = 0; f < 4; f++) {
      f32x4 sa = {};
#pragma unroll
      for (int kc = 0; kc < 2; kc++) {
        int row = f * 16 + cc;
        int idx = row * 8 + ((kc * 4 + g) ^ (cc & 7));
        bf16x8 kf = *(const bf16x8*)&Ks[cur][idx * 8];
        sa = __builtin_amdgcn_mfma_f32_16x16x32_bf16(qf[kc], kf, sa, 0, 0, 0);
      }
      s_acc[f] = sa;
    }

    // register online softmax: row (g*4+r) spans f (in-lane) x cc (16 lanes)
    float p[4][4];
#pragma unroll
    for (int r = 0; r < 4; r++) {
      float mx = fmaxf(fmaxf(s_acc[0][r], s_acc[1][r]), fmaxf(s_acc[2][r], s_acc[3][r]));
      mx = fmaxf(mx, __shfl_xor(mx, 1));
      mx = fmaxf(mx, __shfl_xor(mx, 2));
      mx = fmaxf(mx, __shfl_xor(mx, 4));
      mx = fmaxf(mx, __shfl_xor(mx, 8));
      float nm = fmaxf(m_r[r], mx * 0.125f);
      float alpha = __expf(m_r[r] - nm);
      float rs = 0.f;
#pragma unroll
      for (int f = 0; f < 4; f++) {
        float pv = __expf(s_acc[f][r] * 0.125f - nm);
        p[f][r] = pv;
        rs += pv;
      }
      rs += __shfl_xor(rs, 1);
      rs += __shfl_xor(rs, 2);
      rs += __shfl_xor(rs, 4);
      rs += __shfl_xor(rs, 8);
      l_r[r] = l_r[r] * alpha + rs;
      m_r[r] = nm;
#pragma unroll
      for (int f = 0; f < 4; f++) o_acc[f][r] *= alpha;
    }

    // P bounce: C layout -> A-frag layout (wave-private, no barrier)
#pragma unroll
    for (int f = 0; f < 4; f++)
#pragma unroll
      for (int r = 0; r < 4; r++)
        Pt[wid][(g * 4 + r) * 72 + f * 16 + cc] = f2bf(p[f][r]);
    asm volatile("s_waitcnt lgkmcnt(0)" ::: "memory");
    __builtin_amdgcn_sched_barrier(0);

    bf16x8 pf[2];
#pragma unroll
    for (int kc = 0; kc < 2; kc++)
      pf[kc] = *(const bf16x8*)&Pt[wid][cc * 72 + kc * 32 + g * 8];

    // O += P V   (vf: VT row d = f*16+cc, kv-chunk (kc*4+g), swizzled)
#pragma unroll
    for (int f = 0; f < 4; f++) {
#pragma unroll
      for (int kc = 0; kc < 2; kc++) {
        int row = f * 16 + cc;
        int idx = row * 8 + ((kc * 4 + g) ^ (cc & 7));
        bf16x8 vf = *(const bf16x8*)&Vs[cur][idx * 8];
        o_acc[f] = __builtin_amdgcn_mfma_f32_16x16x32_bf16(pf[kc], vf, o_acc[f], 0, 0, 0);
      }
    }
    cur ^= 1;
  }
#undef A_STAGE

#pragma unroll
  for (int r = 0; r < 4; r++) {
    float li = 1.0f / l_r[r];
#pragma unroll
    for (int f = 0; f < 4; f++)
      O[base + (size_t)(q0 + g * 4 + r) * 64 + f * 16 + cc] = f2bf(o_acc[f][r] * li);
  }
}

// ---------------- residual + LayerNorm -> f32 output ----------------
__global__ __launch_bounds__(256) void ln_gather(
    const u16* __restrict__ emb, const u16* __restrict__ Og,
    const u16* __restrict__ gamma, const u16* __restrict__ beta,
    float* __restrict__ out)
{
  const int row = blockIdx.x;            // b*2048 + s
  const int b = row >> 11, s = row & 2047;
  const int tid = threadIdx.x;
  const size_t ebase = (size_t)row * 1024;
  const size_t obase = ((size_t)(b * 16 + (s >> 7)) << 17) + (size_t)(s & 127) * 1024;
  const int c0 = tid * 4;

  u16x4 ev = *(const u16x4*)&emb[ebase + c0];
  u16x4 zv = *(const u16x4*)&Og[obase + c0];
  float x[4];
  float sum = 0.f, sq = 0.f;
#pragma unroll
  for (int i = 0; i < 4; i++) {
    x[i] = bf2f(ev[i]) + bf2f(zv[i]);
    sum += x[i];
    sq  += x[i] * x[i];
  }
#pragma unroll
  for (int m = 1; m < 64; m <<= 1) { sum += __shfl_xor(sum, m); sq += __shfl_xor(sq, m); }

  __shared__ float red[8];
  const int lane = tid & 63, wid = tid >> 6;
  if (lane == 0) { red[wid] = sum; red[4 + wid] = sq; }
  __syncthreads();
  sum = red[0] + red[1] + red[2] + red[3];
  sq  = red[4] + red[5] + red[6] + red[7];

  float mu  = sum * (1.0f / 1024.0f);
  float var = sq * (1.0f / 1024.0f) - mu * mu;
  float rstd = rsqrtf(var + 1e-5f);

  u16x4 gv  = *(const u16x4*)&gamma[c0];
  u16x4 btv = *(const u16x4*)&beta[c0];
  f32x4 ov;
#pragma unroll
  for (int i = 0; i < 4; i++)
    ov[i] = (x[i] - mu) * rstd * bf2f(gv[i]) + bf2f(btv[i]);
  *(f32x4*)&out[ebase + c0] = ov;
}

extern "C" void kernel_launch(void* const* d_in, const int* in_sizes, int n_in,
                              void* d_out, int out_size, void* d_ws, size_t ws_size,
                              hipStream_t stream) {
  (void)out_size;
  const size_t NEED = 48244736 + 16;
  if (ws_size < NEED) {
    fill_signal<<<16384, 256, 0, stream>>>((float*)d_out, 3000.0f);
    return;
  }
  if (n_in != 9) {
    fill_signal<<<16384, 256, 0, stream>>>((float*)d_out, 2600.0f);
    return;
  }
  const int expect[9] = {4194304, 1048576, 1024, 1048576, 1024, 1048576, 1024, 1024, 1024};
  for (int i = 0; i < 9; i++) {
    if (in_sizes[i] != expect[i]) {
      fill_signal<<<16384, 256, 0, stream>>>((float*)d_out, 2500.0f);
      return;
    }
  }

  u16* ws = (u16*)d_ws;
  int* flags = (int*)((char*)d_ws + 48244736);

  const size_t SZ = (size_t)4194304;
  u16* Qw  = ws + 7345152;
  u16* Kw  = Qw + SZ;
  u16* VTw = Kw + SZ;
  u16* Ow  = VTw + SZ;

  detect_dtype<<<1, 256, 0, stream>>>((const u16*)d_in[0], flags);
  convert_inputs<<<3587, 256, 0, stream>>>(
      d_in[0], d_in[1], d_in[3], d_in[5],
      d_in[2], d_in[4], d_in[6], d_in[7], d_in[8],
      ws, flags);

  dim3 g1(32, 8, 3);
  qkv_gemm<<<g1, 256, 0, stream>>>(ws, Qw, Kw, VTw);
  dim3 g2(32, 32);
  attn<<<g2, 256, 0, stream>>>(Qw, Kw, VTw, Ow);
  ln_gather<<<4096, 256, 0, stream>>>(ws, Ow, ws + 7343104, ws + 7344128,
                                      (float*)d_out);
}

// Round 7
// 148.338 us; speedup vs baseline: 1.2698x; 1.2698x over previous
//
#include <hip/hip_runtime.h>
#include <hip/hip_bf16.h>
#include <hip/hip_fp16.h>

// B=2, S=2048, DIM=1024, H=16, DH=64. Output f32; inputs runtime-detected
// (bf16/f32/f16) and canonicalized to bf16 in ws.
//
// ws layout (bf16 elems):
//  Xc @ 0 | Wq @ 4194304 | Wk @ 5242880 | Wv @ 6291456
//  bq @ 7340032  bk @ 7341056  bv @ 7342080  ga @ 7343104  be @ 7344128
//  Qw @ 7345152 | Kw @ 11539456 | VTw @ 15733760 | Ow @ 19928064
//  flags (4 ints) @ byte 48244736

#define GL_LDS16(g, l) \
  __builtin_amdgcn_global_load_lds((const __attribute__((address_space(1))) void*)(g), \
                                   (__attribute__((address_space(3))) void*)(l), 16, 0, 0)

typedef float f32x4 __attribute__((ext_vector_type(4)));
typedef __bf16 bf16x8 __attribute__((ext_vector_type(8)));
typedef unsigned short u16;
typedef u16 u16x4 __attribute__((ext_vector_type(4)));
typedef u16 u16x8 __attribute__((ext_vector_type(8)));
typedef unsigned int u32;

static __device__ __forceinline__ float bf2f(u16 u) {
  u32 x = ((u32)u) << 16;
  return __builtin_bit_cast(float, x);
}
static __device__ __forceinline__ u16 f2bf(float f) {
  __hip_bfloat16 h = __float2bfloat16(f);
  return __builtin_bit_cast(u16, h);
}

// ---------------- signal (host-detected problems) ----------------
__global__ __launch_bounds__(256) void fill_signal(float* __restrict__ out, float v) {
  int i = blockIdx.x * 256 + threadIdx.x;
  if (i < 4194304) out[i] = v;
}

// ---------------- dtype detection (3-way) ----------------
__global__ __launch_bounds__(256) void detect_dtype(const u16* __restrict__ emb,
                                                    int* __restrict__ flags) {
  const int tid = threadIdx.x;
  u32 maxexp = 0;
  float sum = 0.f, sumsq = 0.f;
  for (int i = 0; i < 64; i++) {
    u16 u = emb[tid * 64 + i];
    u32 e = (u >> 7) & 0xFF;
    maxexp = maxexp > e ? maxexp : e;
    float ef = (float)e;
    sum += ef; sumsq += ef * ef;
  }
  for (int m = 1; m < 64; m <<= 1) {
    u32 o = (u32)__shfl_xor((int)maxexp, m);
    maxexp = maxexp > o ? maxexp : o;
    sum += __shfl_xor(sum, m);
    sumsq += __shfl_xor(sumsq, m);
  }
  __shared__ u32 rm[4];
  __shared__ float rs[4], rq[4];
  if ((tid & 63) == 0) { rm[tid >> 6] = maxexp; rs[tid >> 6] = sum; rq[tid >> 6] = sumsq; }
  __syncthreads();
  if (tid == 0) {
    u32 mx = rm[0]; float s = rs[0], q = rq[0];
    for (int i = 1; i < 4; i++) {
      mx = mx > rm[i] ? mx : rm[i];
      s += rs[i]; q += rq[i];
    }
    int fl;
    if (mx >= 160) fl = 1;                       // f32
    else {
      float mean = s * (1.0f / 16384.0f);
      float var = q * (1.0f / 16384.0f) - mean * mean;
      fl = (var > 60.0f) ? 2 : 0;                // f16 : bf16
    }
    flags[0] = fl;
  }
}

// ---------------- canonicalize inputs to bf16 ----------------
__global__ __launch_bounds__(256) void convert_inputs(
    const void* __restrict__ s0, const void* __restrict__ s1,
    const void* __restrict__ s2, const void* __restrict__ s3,
    const void* __restrict__ s4, const void* __restrict__ s5,
    const void* __restrict__ s6, const void* __restrict__ s7,
    const void* __restrict__ s8,
    u16* __restrict__ ws, const int* __restrict__ flags)
{
  const int t = blockIdx.x * 256 + threadIdx.x;  // unit = 8 elems
  if (t >= 918144) return;
  const void* src; size_t dstoff; int local;
  if      (t < 524288) { src = s0; dstoff = 0;       local = t; }
  else if (t < 655360) { src = s1; dstoff = 4194304; local = t - 524288; }
  else if (t < 786432) { src = s2; dstoff = 5242880; local = t - 655360; }
  else if (t < 917504) { src = s3; dstoff = 6291456; local = t - 786432; }
  else if (t < 917632) { src = s4; dstoff = 7340032; local = t - 917504; }
  else if (t < 917760) { src = s5; dstoff = 7341056; local = t - 917632; }
  else if (t < 917888) { src = s6; dstoff = 7342080; local = t - 917760; }
  else if (t < 918016) { src = s7; dstoff = 7343104; local = t - 917888; }
  else                 { src = s8; dstoff = 7344128; local = t - 918016; }
  const int fl = flags[0];
  u16x8 o;
  if (fl == 1) {
    const float* fp = (const float*)src + (size_t)local * 8;
#pragma unroll
    for (int i = 0; i < 8; i++) o[i] = f2bf(fp[i]);
  } else if (fl == 2) {
    u16x8 hv = *((const u16x8*)src + local);
#pragma unroll
    for (int i = 0; i < 8; i++) {
      u16 tmp = hv[i];
      float v = (float)__builtin_bit_cast(_Float16, tmp);
      o[i] = f2bf(v);
    }
  } else {
    o = *((const u16x8*)src + local);
  }
  *(u16x8*)&ws[dstoff + (size_t)local * 8] = o;
}

// ---------------- fused QKV projection (round-6, measured-good) ----------------
// 128x128 tile, BK=32, 4 waves 2x2. global_load_lds staging, double-buffered,
// chunk-XOR swizzle (linear LDS dest + swizzled source + swizzled read).
__global__ __launch_bounds__(256) void qkv_gemm(
    const u16* __restrict__ ws,
    u16* __restrict__ Qo, u16* __restrict__ Ko, u16* __restrict__ VTo)
{
  __shared__ __align__(16) u16 As[2][128 * 32];
  __shared__ __align__(16) u16 Bs[2][128 * 32];

  const int z = blockIdx.z;
  const u16* X    = ws;
  const u16* W    = ws + 4194304 + (size_t)z * 1048576;
  const u16* bias = ws + 7340032 + (size_t)z * 1024;

  const int tid = threadIdx.x;
  const int lane = tid & 63, wid = tid >> 6;
  const int wm = wid >> 1, wn = wid & 1;
  const int g = lane >> 4, cc = lane & 15;
  const int bm = blockIdx.x * 128, bn = blockIdx.y * 128;

  const int u0 = tid, u1 = tid + 256;
  const int ar0 = u0 >> 2, as0 = u0 & 3;
  const int ar1 = u1 >> 2, as1 = u1 & 3;
  const int ak0 = as0 ^ ((ar0 ^ (ar0 >> 2)) & 3);
  const int ak1 = as1 ^ ((ar1 ^ (ar1 >> 2)) & 3);

  f32x4 acc[4][4] = {};

#define G_STAGE(kt_, b_)                                                      \
  GL_LDS16(X + (size_t)(bm + ar0) * 1024 + (kt_) + ak0 * 8, &As[b_][u0 * 8]); \
  GL_LDS16(X + (size_t)(bm + ar1) * 1024 + (kt_) + ak1 * 8, &As[b_][u1 * 8]); \
  GL_LDS16(W + (size_t)(bn + ar0) * 1024 + (kt_) + ak0 * 8, &Bs[b_][u0 * 8]); \
  GL_LDS16(W + (size_t)(bn + ar1) * 1024 + (kt_) + ak1 * 8, &Bs[b_][u1 * 8]);

  G_STAGE(0, 0);
  int cur = 0;

  for (int kt = 0; kt < 1024; kt += 32) {
    __syncthreads();                 // drains vmcnt: buf[cur] staged
    if (kt + 32 < 1024) { G_STAGE(kt + 32, cur ^ 1); }

    bf16x8 a[4], b[4];
#pragma unroll
    for (int mf = 0; mf < 4; mf++) {
      int row = wm * 64 + mf * 16 + cc;
      int idx = row * 4 + (g ^ ((row ^ (row >> 2)) & 3));
      a[mf] = *(const bf16x8*)&As[cur][idx * 8];
    }
#pragma unroll
    for (int nf = 0; nf < 4; nf++) {
      int col = wn * 64 + nf * 16 + cc;
      int idx = col * 4 + (g ^ ((col ^ (col >> 2)) & 3));
      b[nf] = *(const bf16x8*)&Bs[cur][idx * 8];
    }
#pragma unroll
    for (int mf = 0; mf < 4; mf++)
#pragma unroll
      for (int nf = 0; nf < 4; nf++)
        acc[mf][nf] = __builtin_amdgcn_mfma_f32_16x16x32_bf16(a[mf], b[nf], acc[mf][nf], 0, 0, 0);
    cur ^= 1;
  }
#undef G_STAGE

  float bb[4];
#pragma unroll
  for (int nf = 0; nf < 4; nf++) bb[nf] = bf2f(bias[bn + wn * 64 + nf * 16 + cc]);

#pragma unroll
  for (int mf = 0; mf < 4; mf++) {
#pragma unroll
    for (int nf = 0; nf < 4; nf++) {
      int i0 = bm + wm * 64 + mf * 16 + g * 4;
      int j  = bn + wn * 64 + nf * 16 + cc;
      int h_ = j >> 6, d_ = j & 63;
      if (z == 2) {
        int b_ = i0 >> 11, s_ = i0 & 2047;
        size_t hb = (size_t)(b_ * 16 + h_) * 131072;
        u16x4 pk;
#pragma unroll
        for (int r = 0; r < 4; r++) pk[r] = f2bf(acc[mf][nf][r] + bb[nf]);
        *(u16x4*)&VTo[hb + (size_t)d_ * 2048 + s_] = pk;
      } else {
        u16* dst = z ? Ko : Qo;
#pragma unroll
        for (int r = 0; r < 4; r++) {
          int i = i0 + r;
          int b_ = i >> 11, s_ = i & 2047;
          size_t hb = (size_t)(b_ * 16 + h_) * 131072;
          dst[hb + (size_t)s_ * 64 + d_] = f2bf(acc[mf][nf][r] + bb[nf]);
        }
      }
    }
  }
}

// ---------------- flash attention (round-5 structure + 2 deltas) ----------------
// Deltas vs measured-115us round-5: (1) Sf stride 72->68 f32 (2-way banks),
// (2) Sf/Pt union per wave (LDS 46.6->35.5KB => 4 blocks/CU).
__global__ __launch_bounds__(256) void attn(
    const u16* __restrict__ Q, const u16* __restrict__ K,
    const u16* __restrict__ VT, u16* __restrict__ O)
{
  __shared__ __align__(16) u16 Ks[64 * 72];
  __shared__ __align__(16) u16 Vs[64 * 72];
  __shared__ __align__(16) char SP[4][4352];  // union: Sf f32 stride 68 | Pt u16 stride 72
  __shared__ float Al[4][16];
  __shared__ float Ll[4][16];

  const int tid = threadIdx.x, lane = tid & 63, wid = tid >> 6;
  const int g = lane >> 4, cc = lane & 15;
  const int srow = lane >> 2, sq = lane & 3;
  const int bh = blockIdx.y;
  const int q0 = blockIdx.x * 64 + wid * 16;
  const size_t base = (size_t)bh * 131072;
  float* Sf = (float*)SP[wid];
  u16*   Pt = (u16*)SP[wid];

  bf16x8 qf[2];
#pragma unroll
  for (int kc = 0; kc < 2; kc++)
    qf[kc] = *(const bf16x8*)&Q[base + (size_t)(q0 + cc) * 64 + kc * 32 + g * 8];

  f32x4 o_acc[4] = {};
  float m_s = -1e30f, l_s = 0.f;

  const int kr0 = tid >> 3,         ks0 = tid & 7;
  const int kr1 = (tid + 256) >> 3, ks1 = tid & 7;

  u16x8 rk[2], rv[2];
  rk[0] = *(const u16x8*)&K [base + (size_t)kr0 * 64 + ks0 * 8];
  rk[1] = *(const u16x8*)&K [base + (size_t)kr1 * 64 + ks1 * 8];
  rv[0] = *(const u16x8*)&VT[base + (size_t)kr0 * 2048 + ks0 * 8];
  rv[1] = *(const u16x8*)&VT[base + (size_t)kr1 * 2048 + ks1 * 8];

  for (int kv0 = 0; kv0 < 2048; kv0 += 64) {
    __syncthreads();
    *(u16x8*)&Ks[kr0 * 72 + ks0 * 8] = rk[0];
    *(u16x8*)&Ks[kr1 * 72 + ks1 * 8] = rk[1];
    *(u16x8*)&Vs[kr0 * 72 + ks0 * 8] = rv[0];
    *(u16x8*)&Vs[kr1 * 72 + ks1 * 8] = rv[1];
    __syncthreads();

    if (kv0 + 64 < 2048) {
      int kn = kv0 + 64;
      rk[0] = *(const u16x8*)&K [base + (size_t)(kn + kr0) * 64 + ks0 * 8];
      rk[1] = *(const u16x8*)&K [base + (size_t)(kn + kr1) * 64 + ks1 * 8];
      rv[0] = *(const u16x8*)&VT[base + (size_t)kr0 * 2048 + kn + ks0 * 8];
      rv[1] = *(const u16x8*)&VT[base + (size_t)kr1 * 2048 + kn + ks1 * 8];
    }

    // S = Q K^T
    f32x4 s_acc[4];
#pragma unroll
    for (int f = 0; f < 4; f++) {
      f32x4 sa = {};
#pragma unroll
      for (int kc = 0; kc < 2; kc++) {
        bf16x8 kf = *(const bf16x8*)&Ks[(f * 16 + cc) * 72 + (kc * 4 + g) * 8];
        sa = __builtin_amdgcn_mfma_f32_16x16x32_bf16(qf[kc], kf, sa, 0, 0, 0);
      }
      s_acc[f] = sa;
    }

    // S -> Sf (stride 68: write banks exactly 2-way = free)
#pragma unroll
    for (int f = 0; f < 4; f++)
#pragma unroll
      for (int r = 0; r < 4; r++)
        Sf[(g * 4 + r) * 68 + f * 16 + cc] = s_acc[f][r];
    __syncthreads();

    // softmax: lane owns (row srow, col quarter sq)
    float sv[16];
#pragma unroll
    for (int c = 0; c < 16; c++) sv[c] = Sf[srow * 68 + sq * 16 + c];
    float mx = sv[0];
#pragma unroll
    for (int c = 1; c < 16; c++) mx = fmaxf(mx, sv[c]);
    mx = fmaxf(mx, __shfl_xor(mx, 1));
    mx = fmaxf(mx, __shfl_xor(mx, 2));
    float nm = fmaxf(m_s, mx * 0.125f);
    float alpha = __expf(m_s - nm);
    float pv[16];
    float rs = 0.f;
#pragma unroll
    for (int c = 0; c < 16; c++) {
      pv[c] = __expf(sv[c] * 0.125f - nm);
      rs += pv[c];
    }
    rs += __shfl_xor(rs, 1);
    rs += __shfl_xor(rs, 2);
    l_s = l_s * alpha + rs;
    m_s = nm;
    // P -> Pt (overwrites Sf region; same-wave in-order DS, reads done above)
#pragma unroll
    for (int c = 0; c < 16; c++)
      Pt[srow * 72 + sq * 16 + c] = f2bf(pv[c]);
    if (sq == 0) Al[wid][srow] = alpha;
    __syncthreads();

#pragma unroll
    for (int r = 0; r < 4; r++) {
      float a = Al[wid][g * 4 + r];
#pragma unroll
      for (int f = 0; f < 4; f++) o_acc[f][r] *= a;
    }

    bf16x8 pf[2];
#pragma unroll
    for (int kc = 0; kc < 2; kc++)
      pf[kc] = *(const bf16x8*)&Pt[cc * 72 + kc * 32 + g * 8];

    // O += P V
#pragma unroll
    for (int f = 0; f < 4; f++) {
#pragma unroll
      for (int kc = 0; kc < 2; kc++) {
        bf16x8 vf = *(const bf16x8*)&Vs[(f * 16 + cc) * 72 + (kc * 4 + g) * 8];
        o_acc[f] = __builtin_amdgcn_mfma_f32_16x16x32_bf16(pf[kc], vf, o_acc[f], 0, 0, 0);
      }
    }
  }

  if (sq == 0) Ll[wid][srow] = l_s;
  __syncthreads();

#pragma unroll
  for (int r = 0; r < 4; r++) {
    float li = 1.0f / Ll[wid][g * 4 + r];
#pragma unroll
    for (int f = 0; f < 4; f++)
      O[base + (size_t)(q0 + g * 4 + r) * 64 + f * 16 + cc] = f2bf(o_acc[f][r] * li);
  }
}

// ---------------- residual + LayerNorm -> f32 output ----------------
__global__ __launch_bounds__(256) void ln_gather(
    const u16* __restrict__ emb, const u16* __restrict__ Og,
    const u16* __restrict__ gamma, const u16* __restrict__ beta,
    float* __restrict__ out)
{
  const int row = blockIdx.x;            // b*2048 + s
  const int b = row >> 11, s = row & 2047;
  const int tid = threadIdx.x;
  const size_t ebase = (size_t)row * 1024;
  const size_t obase = ((size_t)(b * 16 + (s >> 7)) << 17) + (size_t)(s & 127) * 1024;
  const int c0 = tid * 4;

  u16x4 ev = *(const u16x4*)&emb[ebase + c0];
  u16x4 zv = *(const u16x4*)&Og[obase + c0];
  float x[4];
  float sum = 0.f, sq = 0.f;
#pragma unroll
  for (int i = 0; i < 4; i++) {
    x[i] = bf2f(ev[i]) + bf2f(zv[i]);
    sum += x[i];
    sq  += x[i] * x[i];
  }
#pragma unroll
  for (int m = 1; m < 64; m <<= 1) { sum += __shfl_xor(sum, m); sq += __shfl_xor(sq, m); }

  __shared__ float red[8];
  const int lane = tid & 63, wid = tid >> 6;
  if (lane == 0) { red[wid] = sum; red[4 + wid] = sq; }
  __syncthreads();
  sum = red[0] + red[1] + red[2] + red[3];
  sq  = red[4] + red[5] + red[6] + red[7];

  float mu  = sum * (1.0f / 1024.0f);
  float var = sq * (1.0f / 1024.0f) - mu * mu;
  float rstd = rsqrtf(var + 1e-5f);

  u16x4 gv  = *(const u16x4*)&gamma[c0];
  u16x4 btv = *(const u16x4*)&beta[c0];
  f32x4 ov;
#pragma unroll
  for (int i = 0; i < 4; i++)
    ov[i] = (x[i] - mu) * rstd * bf2f(gv[i]) + bf2f(btv[i]);
  *(f32x4*)&out[ebase + c0] = ov;
}

extern "C" void kernel_launch(void* const* d_in, const int* in_sizes, int n_in,
                              void* d_out, int out_size, void* d_ws, size_t ws_size,
                              hipStream_t stream) {
  (void)out_size;
  const size_t NEED = 48244736 + 16;
  if (ws_size < NEED) {
    fill_signal<<<16384, 256, 0, stream>>>((float*)d_out, 3000.0f);
    return;
  }
  if (n_in != 9) {
    fill_signal<<<16384, 256, 0, stream>>>((float*)d_out, 2600.0f);
    return;
  }
  const int expect[9] = {4194304, 1048576, 1024, 1048576, 1024, 1048576, 1024, 1024, 1024};
  for (int i = 0; i < 9; i++) {
    if (in_sizes[i] != expect[i]) {
      fill_signal<<<16384, 256, 0, stream>>>((float*)d_out, 2500.0f);
      return;
    }
  }

  u16* ws = (u16*)d_ws;
  int* flags = (int*)((char*)d_ws + 48244736);

  const size_t SZ = (size_t)4194304;
  u16* Qw  = ws + 7345152;
  u16* Kw  = Qw + SZ;
  u16* VTw = Kw + SZ;
  u16* Ow  = VTw + SZ;

  detect_dtype<<<1, 256, 0, stream>>>((const u16*)d_in[0], flags);
  convert_inputs<<<3587, 256, 0, stream>>>(
      d_in[0], d_in[1], d_in[3], d_in[5],
      d_in[2], d_in[4], d_in[6], d_in[7], d_in[8],
      ws, flags);

  dim3 g1(32, 8, 3);
  qkv_gemm<<<g1, 256, 0, stream>>>(ws, Qw, Kw, VTw);
  dim3 g2(32, 32);
  attn<<<g2, 256, 0, stream>>>(Qw, Kw, VTw, Ow);
  ln_gather<<<4096, 256, 0, stream>>>(ws, Ow, ws + 7343104, ws + 7344128,
                                      (float*)d_out);
}

// Round 8
// 132.632 us; speedup vs baseline: 1.4201x; 1.1184x over previous
//
#include <hip/hip_runtime.h>
#include <hip/hip_bf16.h>
#include <hip/hip_fp16.h>

// B=2, S=2048, DIM=1024, H=16, DH=64. Output f32; inputs runtime-detected
// (bf16/f32/f16) and canonicalized to bf16 in ws.
//
// ws layout (bf16 elems):
//  Xc @ 0 | Wq @ 4194304 | Wk @ 5242880 | Wv @ 6291456
//  bq @ 7340032  bk @ 7341056  bv @ 7342080  ga @ 7343104  be @ 7344128
//  Qw @ 7345152 | Kw @ 11539456 | VTw @ 15733760 | Ow @ 19928064
//  flags (4 ints) @ byte 48244736

#define GL_LDS16(g, l) \
  __builtin_amdgcn_global_load_lds((const __attribute__((address_space(1))) void*)(g), \
                                   (__attribute__((address_space(3))) void*)(l), 16, 0, 0)

typedef float f32x4 __attribute__((ext_vector_type(4)));
typedef __bf16 bf16x8 __attribute__((ext_vector_type(8)));
typedef unsigned short u16;
typedef u16 u16x4 __attribute__((ext_vector_type(4)));
typedef u16 u16x8 __attribute__((ext_vector_type(8)));
typedef unsigned int u32;

static __device__ __forceinline__ float bf2f(u16 u) {
  u32 x = ((u32)u) << 16;
  return __builtin_bit_cast(float, x);
}
static __device__ __forceinline__ u16 f2bf(float f) {
  __hip_bfloat16 h = __float2bfloat16(f);
  return __builtin_bit_cast(u16, h);
}

// ---------------- signal (host-detected problems) ----------------
__global__ __launch_bounds__(256) void fill_signal(float* __restrict__ out, float v) {
  int i = blockIdx.x * 256 + threadIdx.x;
  if (i < 4194304) out[i] = v;
}

// ---------------- dtype detection (3-way) ----------------
__global__ __launch_bounds__(256) void detect_dtype(const u16* __restrict__ emb,
                                                    int* __restrict__ flags) {
  const int tid = threadIdx.x;
  u32 maxexp = 0;
  float sum = 0.f, sumsq = 0.f;
  for (int i = 0; i < 64; i++) {
    u16 u = emb[tid * 64 + i];
    u32 e = (u >> 7) & 0xFF;
    maxexp = maxexp > e ? maxexp : e;
    float ef = (float)e;
    sum += ef; sumsq += ef * ef;
  }
  for (int m = 1; m < 64; m <<= 1) {
    u32 o = (u32)__shfl_xor((int)maxexp, m);
    maxexp = maxexp > o ? maxexp : o;
    sum += __shfl_xor(sum, m);
    sumsq += __shfl_xor(sumsq, m);
  }
  __shared__ u32 rm[4];
  __shared__ float rs[4], rq[4];
  if ((tid & 63) == 0) { rm[tid >> 6] = maxexp; rs[tid >> 6] = sum; rq[tid >> 6] = sumsq; }
  __syncthreads();
  if (tid == 0) {
    u32 mx = rm[0]; float s = rs[0], q = rq[0];
    for (int i = 1; i < 4; i++) {
      mx = mx > rm[i] ? mx : rm[i];
      s += rs[i]; q += rq[i];
    }
    int fl;
    if (mx >= 160) fl = 1;                       // f32
    else {
      float mean = s * (1.0f / 16384.0f);
      float var = q * (1.0f / 16384.0f) - mean * mean;
      fl = (var > 60.0f) ? 2 : 0;                // f16 : bf16
    }
    flags[0] = fl;
  }
}

// ---------------- canonicalize inputs to bf16 ----------------
__global__ __launch_bounds__(256) void convert_inputs(
    const void* __restrict__ s0, const void* __restrict__ s1,
    const void* __restrict__ s2, const void* __restrict__ s3,
    const void* __restrict__ s4, const void* __restrict__ s5,
    const void* __restrict__ s6, const void* __restrict__ s7,
    const void* __restrict__ s8,
    u16* __restrict__ ws, const int* __restrict__ flags)
{
  const int t = blockIdx.x * 256 + threadIdx.x;  // unit = 8 elems
  if (t >= 918144) return;
  const void* src; size_t dstoff; int local;
  if      (t < 524288) { src = s0; dstoff = 0;       local = t; }
  else if (t < 655360) { src = s1; dstoff = 4194304; local = t - 524288; }
  else if (t < 786432) { src = s2; dstoff = 5242880; local = t - 655360; }
  else if (t < 917504) { src = s3; dstoff = 6291456; local = t - 786432; }
  else if (t < 917632) { src = s4; dstoff = 7340032; local = t - 917504; }
  else if (t < 917760) { src = s5; dstoff = 7341056; local = t - 917632; }
  else if (t < 917888) { src = s6; dstoff = 7342080; local = t - 917760; }
  else if (t < 918016) { src = s7; dstoff = 7343104; local = t - 917888; }
  else                 { src = s8; dstoff = 7344128; local = t - 918016; }
  const int fl = flags[0];
  u16x8 o;
  if (fl == 1) {
    const float* fp = (const float*)src + (size_t)local * 8;
#pragma unroll
    for (int i = 0; i < 8; i++) o[i] = f2bf(fp[i]);
  } else if (fl == 2) {
    u16x8 hv = *((const u16x8*)src + local);
#pragma unroll
    for (int i = 0; i < 8; i++) {
      u16 tmp = hv[i];
      float v = (float)__builtin_bit_cast(_Float16, tmp);
      o[i] = f2bf(v);
    }
  } else {
    o = *((const u16x8*)src + local);
  }
  *(u16x8*)&ws[dstoff + (size_t)local * 8] = o;
}

// ---------------- fused QKV projection (round-6, measured-good) ----------------
__global__ __launch_bounds__(256) void qkv_gemm(
    const u16* __restrict__ ws,
    u16* __restrict__ Qo, u16* __restrict__ Ko, u16* __restrict__ VTo)
{
  __shared__ __align__(16) u16 As[2][128 * 32];
  __shared__ __align__(16) u16 Bs[2][128 * 32];

  const int z = blockIdx.z;
  const u16* X    = ws;
  const u16* W    = ws + 4194304 + (size_t)z * 1048576;
  const u16* bias = ws + 7340032 + (size_t)z * 1024;

  const int tid = threadIdx.x;
  const int lane = tid & 63, wid = tid >> 6;
  const int wm = wid >> 1, wn = wid & 1;
  const int g = lane >> 4, cc = lane & 15;
  const int bm = blockIdx.x * 128, bn = blockIdx.y * 128;

  const int u0 = tid, u1 = tid + 256;
  const int ar0 = u0 >> 2, as0 = u0 & 3;
  const int ar1 = u1 >> 2, as1 = u1 & 3;
  const int ak0 = as0 ^ ((ar0 ^ (ar0 >> 2)) & 3);
  const int ak1 = as1 ^ ((ar1 ^ (ar1 >> 2)) & 3);

  f32x4 acc[4][4] = {};

#define G_STAGE(kt_, b_)                                                      \
  GL_LDS16(X + (size_t)(bm + ar0) * 1024 + (kt_) + ak0 * 8, &As[b_][u0 * 8]); \
  GL_LDS16(X + (size_t)(bm + ar1) * 1024 + (kt_) + ak1 * 8, &As[b_][u1 * 8]); \
  GL_LDS16(W + (size_t)(bn + ar0) * 1024 + (kt_) + ak0 * 8, &Bs[b_][u0 * 8]); \
  GL_LDS16(W + (size_t)(bn + ar1) * 1024 + (kt_) + ak1 * 8, &Bs[b_][u1 * 8]);

  G_STAGE(0, 0);
  int cur = 0;

  for (int kt = 0; kt < 1024; kt += 32) {
    __syncthreads();                 // drains vmcnt: buf[cur] staged
    if (kt + 32 < 1024) { G_STAGE(kt + 32, cur ^ 1); }

    bf16x8 a[4], b[4];
#pragma unroll
    for (int mf = 0; mf < 4; mf++) {
      int row = wm * 64 + mf * 16 + cc;
      int idx = row * 4 + (g ^ ((row ^ (row >> 2)) & 3));
      a[mf] = *(const bf16x8*)&As[cur][idx * 8];
    }
#pragma unroll
    for (int nf = 0; nf < 4; nf++) {
      int col = wn * 64 + nf * 16 + cc;
      int idx = col * 4 + (g ^ ((col ^ (col >> 2)) & 3));
      b[nf] = *(const bf16x8*)&Bs[cur][idx * 8];
    }
#pragma unroll
    for (int mf = 0; mf < 4; mf++)
#pragma unroll
      for (int nf = 0; nf < 4; nf++)
        acc[mf][nf] = __builtin_amdgcn_mfma_f32_16x16x32_bf16(a[mf], b[nf], acc[mf][nf], 0, 0, 0);
    cur ^= 1;
  }
#undef G_STAGE

  float bb[4];
#pragma unroll
  for (int nf = 0; nf < 4; nf++) bb[nf] = bf2f(bias[bn + wn * 64 + nf * 16 + cc]);

#pragma unroll
  for (int mf = 0; mf < 4; mf++) {
#pragma unroll
    for (int nf = 0; nf < 4; nf++) {
      int i0 = bm + wm * 64 + mf * 16 + g * 4;
      int j  = bn + wn * 64 + nf * 16 + cc;
      int h_ = j >> 6, d_ = j & 63;
      if (z == 2) {
        int b_ = i0 >> 11, s_ = i0 & 2047;
        size_t hb = (size_t)(b_ * 16 + h_) * 131072;
        u16x4 pk;
#pragma unroll
        for (int r = 0; r < 4; r++) pk[r] = f2bf(acc[mf][nf][r] + bb[nf]);
        *(u16x4*)&VTo[hb + (size_t)d_ * 2048 + s_] = pk;
      } else {
        u16* dst = z ? Ko : Qo;
#pragma unroll
        for (int r = 0; r < 4; r++) {
          int i = i0 + r;
          int b_ = i >> 11, s_ = i & 2047;
          size_t hb = (size_t)(b_ * 16 + h_) * 131072;
          dst[hb + (size_t)s_ * 64 + d_] = f2bf(acc[mf][nf][r] + bb[nf]);
        }
      }
    }
  }
}

// ---------------- flash attention: swapped-QK^T, in-register softmax ----------------
// S^T = mfma(K, Q): lane(g,cc) holds S[kv=f*16+g*4+r][q=cc] -> softmax state
// (m,l,alpha) is lane-local for q=cc (replicated over g via shfl 16/32).
// PV as O^T = mfma(V^T, P): o_acc[f2][r] = O[q0+cc][d=f2*16+g*4+r].
__global__ __launch_bounds__(256) void attn(
    const u16* __restrict__ Q, const u16* __restrict__ K,
    const u16* __restrict__ VT, u16* __restrict__ O)
{
  __shared__ __align__(16) u16 Ks[64 * 72];
  __shared__ __align__(16) u16 Vs[64 * 72];
  __shared__ __align__(16) u16 Pt[4][16 * 72];   // per-wave: [q=cc][kv]

  const int tid = threadIdx.x, lane = tid & 63, wid = tid >> 6;
  const int g = lane >> 4, cc = lane & 15;
  const int bh = blockIdx.y;
  const int q0 = blockIdx.x * 64 + wid * 16;
  const size_t base = (size_t)bh * 131072;

  bf16x8 qf[2];
#pragma unroll
  for (int kc = 0; kc < 2; kc++)
    qf[kc] = *(const bf16x8*)&Q[base + (size_t)(q0 + cc) * 64 + kc * 32 + g * 8];

  f32x4 o_acc[4] = {};
  float m_s = -1e30f, l_s = 0.f;      // for q = q0+cc

  const int kr0 = tid >> 3,         ks0 = tid & 7;
  const int kr1 = (tid + 256) >> 3, ks1 = tid & 7;

  u16x8 rk[2], rv[2];
  rk[0] = *(const u16x8*)&K [base + (size_t)kr0 * 64 + ks0 * 8];
  rk[1] = *(const u16x8*)&K [base + (size_t)kr1 * 64 + ks1 * 8];
  rv[0] = *(const u16x8*)&VT[base + (size_t)kr0 * 2048 + ks0 * 8];
  rv[1] = *(const u16x8*)&VT[base + (size_t)kr1 * 2048 + ks1 * 8];

  for (int kv0 = 0; kv0 < 2048; kv0 += 64) {
    __syncthreads();
    *(u16x8*)&Ks[kr0 * 72 + ks0 * 8] = rk[0];
    *(u16x8*)&Ks[kr1 * 72 + ks1 * 8] = rk[1];
    *(u16x8*)&Vs[kr0 * 72 + ks0 * 8] = rv[0];
    *(u16x8*)&Vs[kr1 * 72 + ks1 * 8] = rv[1];
    __syncthreads();

    if (kv0 + 64 < 2048) {
      int kn = kv0 + 64;
      rk[0] = *(const u16x8*)&K [base + (size_t)(kn + kr0) * 64 + ks0 * 8];
      rk[1] = *(const u16x8*)&K [base + (size_t)(kn + kr1) * 64 + ks1 * 8];
      rv[0] = *(const u16x8*)&VT[base + (size_t)kr0 * 2048 + kn + ks0 * 8];
      rv[1] = *(const u16x8*)&VT[base + (size_t)kr1 * 2048 + kn + ks1 * 8];
    }

    // S^T = K·Q^T: A-frag = K rows (kv), B-frag = Q rows (q)
    f32x4 s_acc[4];
#pragma unroll
    for (int f = 0; f < 4; f++) {
      f32x4 sa = {};
#pragma unroll
      for (int kc = 0; kc < 2; kc++) {
        bf16x8 kf = *(const bf16x8*)&Ks[(f * 16 + cc) * 72 + kc * 32 + g * 8];
        sa = __builtin_amdgcn_mfma_f32_16x16x32_bf16(kf, qf[kc], sa, 0, 0, 0);
      }
      s_acc[f] = sa;
    }

    // in-register online softmax over kv for q=cc
    float mx = s_acc[0][0];
#pragma unroll
    for (int f = 0; f < 4; f++)
#pragma unroll
      for (int r = 0; r < 4; r++) mx = fmaxf(mx, s_acc[f][r]);
    mx = fmaxf(mx, __shfl_xor(mx, 16));
    mx = fmaxf(mx, __shfl_xor(mx, 32));
    float nm = fmaxf(m_s, mx * 0.125f);
    float alpha = __expf(m_s - nm);
    float p[4][4];
    float rs = 0.f;
#pragma unroll
    for (int f = 0; f < 4; f++)
#pragma unroll
      for (int r = 0; r < 4; r++) {
        float pv = __expf(s_acc[f][r] * 0.125f - nm);
        p[f][r] = pv;
        rs += pv;
      }
    rs += __shfl_xor(rs, 16);
    rs += __shfl_xor(rs, 32);
    l_s = l_s * alpha + rs;
    m_s = nm;

    // P -> wave-private Pt[q=cc][kv], 4x ds_write_b64 (2-way banks: free)
#pragma unroll
    for (int f = 0; f < 4; f++) {
      u16x4 pk;
#pragma unroll
      for (int r = 0; r < 4; r++) pk[r] = f2bf(p[f][r]);
      *(u16x4*)&Pt[wid][cc * 72 + f * 16 + g * 4] = pk;
    }
    asm volatile("s_waitcnt lgkmcnt(0)" ::: "memory");
    __builtin_amdgcn_sched_barrier(0);

    bf16x8 pf[2];
#pragma unroll
    for (int kc = 0; kc < 2; kc++)
      pf[kc] = *(const bf16x8*)&Pt[wid][cc * 72 + kc * 32 + g * 8];

    // rescale O (lane-local alpha)
#pragma unroll
    for (int f = 0; f < 4; f++)
#pragma unroll
      for (int r = 0; r < 4; r++) o_acc[f][r] *= alpha;

    // O^T += V^T·P^T : A-frag = V^T rows (d), B-frag = P rows (q)
#pragma unroll
    for (int f2 = 0; f2 < 4; f2++) {
#pragma unroll
      for (int kc = 0; kc < 2; kc++) {
        bf16x8 vf = *(const bf16x8*)&Vs[(f2 * 16 + cc) * 72 + kc * 32 + g * 8];
        o_acc[f2] = __builtin_amdgcn_mfma_f32_16x16x32_bf16(vf, pf[kc], o_acc[f2], 0, 0, 0);
      }
    }
  }

  // epilogue: O[q0+cc][d = f2*16 + g*4 + r] = o_acc[f2][r] / l
  float li = 1.0f / l_s;
#pragma unroll
  for (int f2 = 0; f2 < 4; f2++) {
    u16x4 ov;
#pragma unroll
    for (int r = 0; r < 4; r++) ov[r] = f2bf(o_acc[f2][r] * li);
    *(u16x4*)&O[base + (size_t)(q0 + cc) * 64 + f2 * 16 + g * 4] = ov;
  }
}

// ---------------- residual + LayerNorm -> f32 output ----------------
__global__ __launch_bounds__(256) void ln_gather(
    const u16* __restrict__ emb, const u16* __restrict__ Og,
    const u16* __restrict__ gamma, const u16* __restrict__ beta,
    float* __restrict__ out)
{
  const int row = blockIdx.x;            // b*2048 + s
  const int b = row >> 11, s = row & 2047;
  const int tid = threadIdx.x;
  const size_t ebase = (size_t)row * 1024;
  const size_t obase = ((size_t)(b * 16 + (s >> 7)) << 17) + (size_t)(s & 127) * 1024;
  const int c0 = tid * 4;

  u16x4 ev = *(const u16x4*)&emb[ebase + c0];
  u16x4 zv = *(const u16x4*)&Og[obase + c0];
  float x[4];
  float sum = 0.f, sq = 0.f;
#pragma unroll
  for (int i = 0; i < 4; i++) {
    x[i] = bf2f(ev[i]) + bf2f(zv[i]);
    sum += x[i];
    sq  += x[i] * x[i];
  }
#pragma unroll
  for (int m = 1; m < 64; m <<= 1) { sum += __shfl_xor(sum, m); sq += __shfl_xor(sq, m); }

  __shared__ float red[8];
  const int lane = tid & 63, wid = tid >> 6;
  if (lane == 0) { red[wid] = sum; red[4 + wid] = sq; }
  __syncthreads();
  sum = red[0] + red[1] + red[2] + red[3];
  sq  = red[4] + red[5] + red[6] + red[7];

  float mu  = sum * (1.0f / 1024.0f);
  float var = sq * (1.0f / 1024.0f) - mu * mu;
  float rstd = rsqrtf(var + 1e-5f);

  u16x4 gv  = *(const u16x4*)&gamma[c0];
  u16x4 btv = *(const u16x4*)&beta[c0];
  f32x4 ov;
#pragma unroll
  for (int i = 0; i < 4; i++)
    ov[i] = (x[i] - mu) * rstd * bf2f(gv[i]) + bf2f(btv[i]);
  *(f32x4*)&out[ebase + c0] = ov;
}

extern "C" void kernel_launch(void* const* d_in, const int* in_sizes, int n_in,
                              void* d_out, int out_size, void* d_ws, size_t ws_size,
                              hipStream_t stream) {
  (void)out_size;
  const size_t NEED = 48244736 + 16;
  if (ws_size < NEED) {
    fill_signal<<<16384, 256, 0, stream>>>((float*)d_out, 3000.0f);
    return;
  }
  if (n_in != 9) {
    fill_signal<<<16384, 256, 0, stream>>>((float*)d_out, 2600.0f);
    return;
  }
  const int expect[9] = {4194304, 1048576, 1024, 1048576, 1024, 1048576, 1024, 1024, 1024};
  for (int i = 0; i < 9; i++) {
    if (in_sizes[i] != expect[i]) {
      fill_signal<<<16384, 256, 0, stream>>>((float*)d_out, 2500.0f);
      return;
    }
  }

  u16* ws = (u16*)d_ws;
  int* flags = (int*)((char*)d_ws + 48244736);

  const size_t SZ = (size_t)4194304;
  u16* Qw  = ws + 7345152;
  u16* Kw  = Qw + SZ;
  u16* VTw = Kw + SZ;
  u16* Ow  = VTw + SZ;

  detect_dtype<<<1, 256, 0, stream>>>((const u16*)d_in[0], flags);
  convert_inputs<<<3587, 256, 0, stream>>>(
      d_in[0], d_in[1], d_in[3], d_in[5],
      d_in[2], d_in[4], d_in[6], d_in[7], d_in[8],
      ws, flags);

  dim3 g1(32, 8, 3);
  qkv_gemm<<<g1, 256, 0, stream>>>(ws, Qw, Kw, VTw);
  dim3 g2(32, 32);
  attn<<<g2, 256, 0, stream>>>(Qw, Kw, VTw, Ow);
  ln_gather<<<4096, 256, 0, stream>>>(ws, Ow, ws + 7343104, ws + 7344128,
                                      (float*)d_out);
}